// Round 9
// baseline (171.654 us; speedup 1.0000x reference)
//
#include <hip/hip_runtime.h>
#include <hip/hip_bf16.h>

// Problem constants
#define BB 2
#define LL 2048
#define DD 1024
#define HH 16
#define FD 16
#define HD 64
#define EPS 1e-5f
#define RQKV 1536   // fused QKV row stride (256 Q + 256 K + 1024 V)
#define NFIX 4      // first NFIX positions per (b,h) recomputed in fp32 (low-z rows)

typedef __attribute__((ext_vector_type(4))) float f32x4;
typedef __attribute__((ext_vector_type(8))) _Float16 f16x8;
typedef __attribute__((ext_vector_type(4))) _Float16 f16x4;
typedef __attribute__((ext_vector_type(4))) unsigned int u32x4;

// ---------------------------------------------------------------------------
// prep: fused pre-pass, branch on block range (round-15/16 verified).
//   [0,1536):    transpose+cast [Wq|Wk|Wv] -> WqkvT fp16 [1536][1024]
//   [1536,2560): transpose+cast Wo -> WoT fp16 [1024][1024]
//   [2560,2608): early_qkv — QKVe[8][1536] = hs_early[8][1024] @ W, fp32
//     (early rows must come from fp32 inputs: fp16-sourced q,k give |ds|~4e-4,
//      which s^2/(z+eps) amplifies to ~0.1 output error on low-z rows.)
//   [2608,3632): cast hs fp32 -> HS16 fp16 (shared A operand pre-cast ONCE —
//      round 14 proved folding this into the multi-reuse GEMM doubles HBM).
//
// SESSION LEDGER (do not re-try without new counter evidence):
//   * FIXA fusion of fix_final into O-GEMM: +15.6 us (rounds 6/7) — template
//     + hot-loop branch perturbs GEMM codegen for BOTH instantiations.
//   * balanced-qt y-permutation: no gain (round 6 vs 7) — dispatch model
//     unverified; CU-balancing via y-permutation is a dead end.
//   * vtrans pre-transposed V + b64 staging: +1.6 us net (round 4).
//   * permlane-based S^2 transpose: WRONG (round 2) — k-slot map unpinned.
//   * round-3 config = 165.6/165.8 us (rounds 3/8): the verified anchor.
//   * round 9: GEMM tile 128x64 -> 128x128, same reg-staged structure
//     (ladder precedent m92->m93: 343->517 TF from tile growth alone).
// ---------------------------------------------------------------------------
__global__ __launch_bounds__(256) void prep(
    const float* __restrict__ Wq, const float* __restrict__ Wk,
    const float* __restrict__ Wv, const float* __restrict__ Wo,
    const float* __restrict__ hs, _Float16* __restrict__ WqkvT,
    _Float16* __restrict__ WoT, float* __restrict__ QKVe,
    _Float16* __restrict__ HS16) {
  __shared__ __attribute__((aligned(16))) char smem[40960];
  const int bx = blockIdx.x;
  const int tid = threadIdx.x;

  if (bx >= 2608) {
    // ---- cast_hs path ----
    int idx = ((bx - 2608) * 256 + tid) * 16;
#pragma unroll
    for (int half = 0; half < 2; half++) {
      float4 a = *(const float4*)(hs + idx + half * 8);
      float4 b = *(const float4*)(hs + idx + half * 8 + 4);
      f16x8 p = {(_Float16)a.x, (_Float16)a.y, (_Float16)a.z, (_Float16)a.w,
                 (_Float16)b.x, (_Float16)b.y, (_Float16)b.z, (_Float16)b.w};
      *(f16x8*)(HS16 + idx + half * 8) = p;
    }
    return;
  }

  if (bx < 2560) {
    // ---- transpose+cast path ----
    _Float16(*s)[40] = (_Float16(*)[40])smem;
    const float* src;
    _Float16* dst;
    int n0, ncol, drow, k0;
    if (bx < 1536) {
      int ct = bx % 48, kt = bx / 48;
      if (ct < 8) { src = Wq; n0 = ct * 32; ncol = 256; drow = n0; }
      else if (ct < 16) { src = Wk; n0 = (ct - 8) * 32; ncol = 256; drow = 256 + n0; }
      else { src = Wv; n0 = (ct - 16) * 32; ncol = 1024; drow = 512 + n0; }
      k0 = kt * 32;
      dst = WqkvT;
    } else {
      int i2 = bx - 1536;
      n0 = (i2 & 31) * 32; k0 = (i2 >> 5) * 32;
      src = Wo; ncol = DD; drow = n0; dst = WoT;
    }
    {
      int r = tid >> 3, c = (tid & 7) * 4;
      float4 v = *(const float4*)(src + (size_t)(k0 + r) * ncol + n0 + c);
      f16x4 p = {(_Float16)v.x, (_Float16)v.y, (_Float16)v.z, (_Float16)v.w};
      *(f16x4*)&s[r][c] = p;
    }
    __syncthreads();
    {
      int n = tid >> 3, kk = (tid & 7) * 4;
      f16x4 o = {s[kk + 0][n], s[kk + 1][n], s[kk + 2][n], s[kk + 3][n]};
      *(f16x4*)(dst + (size_t)(drow + n) * DD + k0 + kk) = o;
    }
    return;
  }

  // ---- early_qkv path ----
  float(*sHS)[DD] = (float(*)[DD])smem;                      // 32 KB
  float(*part)[8][32] = (float(*)[8][32])(smem + 32768);     // 8 KB
  const int kg = tid >> 5, c = tid & 31;
  const int c0 = (bx - 2560) * 32;

  for (int i = tid; i < 8 * (DD / 4); i += 256) {
    int e = i / (DD / 4), col4 = (i % (DD / 4)) * 4;
    int b = e >> 2, r = e & 3;
    *(float4*)&sHS[e][col4] =
        *(const float4*)(hs + (size_t)(b * LL + r) * DD + col4);
  }
  __syncthreads();

  const float* W;
  int col, ncol;
  if (c0 < 256) { W = Wq; col = c0 + c; ncol = 256; }
  else if (c0 < 512) { W = Wk; col = (c0 - 256) + c; ncol = 256; }
  else { W = Wv; col = (c0 - 512) + c; ncol = 1024; }

  float acc[8] = {};
  const int d0 = kg * 128;
#pragma unroll 4
  for (int d = d0; d < d0 + 128; d++) {
    float wv = W[(size_t)d * ncol + col];
#pragma unroll
    for (int e = 0; e < 8; e++) acc[e] += sHS[e][d] * wv;
  }
#pragma unroll
  for (int e = 0; e < 8; e++) part[kg][e][c] = acc[e];
  __syncthreads();

  {
    int e = tid >> 5;
    float t = 0.f;
#pragma unroll
    for (int g = 0; g < 8; g++) t += part[g][e][c];
    QKVe[(size_t)e * RQKV + c0 + c] = t;
  }
}

// ---------------------------------------------------------------------------
// fp16 MFMA GEMM, round 9: 128x128 tile (was 128x64), same verified
// structure — BK=64, 4 waves (2x2, wave tile now 64x64, acc 4x4), register
// prefetch of the next 64-K slab, XOR-swizzled LDS, 2 barriers/K-step.
// B is staged by all 256 threads exactly symmetric to A (the old tid<128
// conditional is gone). Fragment XOR-column formula, MFMA conventions and
// epilogue mapping are byte-identical to the verified kernel -> numerics
// bit-identical. Mechanism: per-wave MFMA/K-step 16 -> 32 at the same
// per-thread staging volume (ladder m92->m93 precedent: +51%).
// Ledger: DMA staging / 64x64 tiles / fp32-A fusion / FIXA all measured
// regressions — do not re-introduce.
// ---------------------------------------------------------------------------
template <typename OutT>
__global__ __launch_bounds__(256) void gemm_f16(
    const _Float16* __restrict__ A, const _Float16* __restrict__ Bt,
    OutT* __restrict__ C, int M, int N, int K) {
  __shared__ __attribute__((aligned(16))) _Float16 sA[128 * 64];  // 16 KB
  __shared__ __attribute__((aligned(16))) _Float16 sB[128 * 64];  // 16 KB
  const int tid = threadIdx.x;
  const int m0 = blockIdx.y * 128, n0 = blockIdx.x * 128;
  const int w = tid >> 6, lane = tid & 63, quad = lane >> 4, l16 = lane & 15;
  const int wm = (w >> 1) * 64, wn = (w & 1) * 64;

  const int sr = tid >> 1, p = tid & 1;     // staging: row 0..127, half p
  const _Float16* Ag = A + (size_t)(m0 + sr) * K + p * 32;
  const _Float16* Bg = Bt + (size_t)(n0 + sr) * K + p * 32;
  _Float16* sAw = &sA[sr * 64];
  _Float16* sBw = &sB[sr * 64];
  const int swz = sr & 7;

  f32x4 acc[4][4];
#pragma unroll
  for (int i = 0; i < 4; i++)
#pragma unroll
    for (int j = 0; j < 4; j++) acc[i][j] = (f32x4){0.f, 0.f, 0.f, 0.f};

  f16x8 ar[4], br[4];
  auto LOAD = [&](int k0) {
#pragma unroll
    for (int i = 0; i < 4; i++) ar[i] = *(const f16x8*)(Ag + k0 + i * 8);
#pragma unroll
    for (int i = 0; i < 4; i++) br[i] = *(const f16x8*)(Bg + k0 + i * 8);
  };
  LOAD(0);

  for (int k0 = 0; k0 < K; k0 += 64) {
    __syncthreads();
#pragma unroll
    for (int i = 0; i < 4; i++)
      *(f16x8*)(sAw + (((4 * p + i) ^ swz) * 8)) = ar[i];
#pragma unroll
    for (int i = 0; i < 4; i++)
      *(f16x8*)(sBw + (((4 * p + i) ^ swz) * 8)) = br[i];
    __syncthreads();
    if (k0 + 64 < K) LOAD(k0 + 64);  // prefetch overlaps the MFMAs below

#pragma unroll
    for (int s = 0; s < 2; s++) {
      f16x8 af[4], bf[4];
#pragma unroll
      for (int i = 0; i < 4; i++) {
        int row = wm + i * 16 + l16;
        int col = ((s * 4 + quad) ^ (row & 7)) * 8;
        af[i] = *(const f16x8*)&sA[row * 64 + col];
      }
#pragma unroll
      for (int j = 0; j < 4; j++) {
        int row = wn + j * 16 + l16;
        int col = ((s * 4 + quad) ^ (row & 7)) * 8;
        bf[j] = *(const f16x8*)&sB[row * 64 + col];
      }
#pragma unroll
      for (int i = 0; i < 4; i++)
#pragma unroll
        for (int j = 0; j < 4; j++)
          acc[i][j] = __builtin_amdgcn_mfma_f32_16x16x32_f16(af[i], bf[j], acc[i][j], 0, 0, 0);
    }
  }

#pragma unroll
  for (int i = 0; i < 4; i++)
#pragma unroll
    for (int j = 0; j < 4; j++)
#pragma unroll
      for (int r = 0; r < 4; r++) {
        const int row = m0 + wm + i * 16 + quad * 4 + r;
        const int col = n0 + wn + j * 16 + l16;
        C[(size_t)row * N + col] = (OutT)acc[i][j][r];
      }
}

__device__ __forceinline__ unsigned pack_f16x2(float a, float b) {
  unsigned short ua = __builtin_bit_cast(unsigned short, (_Float16)a);  // RTN
  unsigned short ub = __builtin_bit_cast(unsigned short, (_Float16)b);  // RTN
  return (unsigned)ua | ((unsigned)ub << 16);
}

// ---------------------------------------------------------------------------
// MFMA causal quadratic attention (round-3 verified, byte-identical):
// in-register S^2, NO cross-lane ops, layout-agnostic by construction:
//   * swapped QK^T: mfma(kf, qfrag) -> lane(Q,l16) holds
//     S[key=16nt+4Q+r][q=l16]. A-row = l&15 = q already matches the PV
//     A-fragment row — no lane redistribution needed at all.
//   * af0 = {wp0w0,wp0w1,wp1w0,wp1w1}: slot(Q,i) holds key
//     kappa = 16*(i>>2) + 4Q + (i&3) for the lane's own q.
//   * V staged into slot-permuted LDS columns col(k) =
//     (k&32)|((k&12)<<1)|((k&16)>>2)|(k&3), so the UNCHANGED b128 vf reads
//     present V[kappa] at slot(Q,i) — A/B slot-consistent under ANY hw slot
//     map (products pair S2[kappa]*V[kappa], kappa bijective over 32 keys).
//   * z ones-trick is slot-permutation-invariant (B=1 at every slot).
//   * causal mask in swapped form: key = k0+16nt+4Q+r vs q = gq+l16.
// LDS 27.25 KB -> 5 blocks/CU.
// ---------------------------------------------------------------------------
#define SK5 24    // sK row stride: 16 f16 + 8 pad
#define SV5 136   // sVt row stride: 128 keys + 8 pad

__global__ __launch_bounds__(256, 5) void attn_mfma7(
    const _Float16* __restrict__ QKV, _Float16* __restrict__ O) {
  __shared__ __attribute__((aligned(16))) _Float16 sK[128 * SK5];     // 6.0 KB
  __shared__ __attribute__((aligned(16))) _Float16 sVt[80 * SV5];     // 21.25 KB

  const int bh = blockIdx.x;           // fast grid dim: all qt of a bh -> one XCD
  const int b = bh >> 4, h = bh & 15;
  const int qt = 31 - blockIdx.y;      // heavy-first dispatch order
  const int tid = threadIdx.x;
  const int w = tid >> 6;
  const int lane = tid & 63;
  const int quad = lane >> 4;
  const int l16 = lane & 15;
  const int gq = qt * 64 + w * 16;

  // slot-permuted V column for this lane's staged key (see header comment)
  const int pc = (lane & 32) | ((lane & 12) << 1) | ((lane & 16) >> 2) | (lane & 3);

  f16x8 qfrag = {};
  if (quad < 2) {
    qfrag = *(const f16x8*)(QKV +
        (size_t)(b * LL + gq + l16) * RQKV + h * FD + quad * 8);
    const _Float16 RT2 = (_Float16)1.41421356f;
#pragma unroll
    for (int i = 0; i < 8; i++) qfrag[i] = qfrag[i] * RT2;
  }

  // ones rows 64..79 of sVt drive the z row-sum MFMA (all slots = 1 at col 0)
  for (int t = tid; t < 16 * SV5; t += 256) {
    int r = t / SV5, c = t % SV5;
    sVt[64 * SV5 + t] = (_Float16)((r == 0 && c < 128) ? 1.0f : 0.0f);
  }
  __syncthreads();
  const f16x8 zf0 = *(const f16x8*)&sVt[(64 + l16) * SV5 + quad * 8];
  const f16x8 zf1 = *(const f16x8*)&sVt[(64 + l16) * SV5 + 32 + quad * 8];

  f32x4 oacc[4];
  f32x4 zacc = (f32x4){0.f, 0.f, 0.f, 0.f};
#pragma unroll
  for (int nt = 0; nt < 4; nt++) oacc[nt] = (f32x4){0.f, 0.f, 0.f, 0.f};

  const int nst = qt + 1;          // 64-key subtiles needed
  const int nkt = (nst + 1) >> 1;  // 128-key staging tiles

  // 128-key prefetch: K rows via (tid>>1), V rows via lane (two 64-row halves)
  const int krow = tid >> 1, kcol = (tid & 1) * 8;
  f16x8 kreg;
  f16x8 vreg0, vreg1, vreg2, vreg3;
  auto LOAD = [&](int kt) {
    kreg = *(const f16x8*)(QKV +
        (size_t)(b * LL + kt * 128 + krow) * RQKV + 256 + h * FD + kcol);
    const _Float16* vp = QKV +
        (size_t)(b * LL + kt * 128 + lane) * RQKV + 512 + h * HD + w * 16;
    vreg0 = *(const f16x8*)vp;
    vreg1 = *(const f16x8*)(vp + 8);
    vp += (size_t)64 * RQKV;
    vreg2 = *(const f16x8*)vp;
    vreg3 = *(const f16x8*)(vp + 8);
  };
  LOAD(0);

  for (int kt = 0; kt < nkt; kt++) {
    __syncthreads();
    *(f16x8*)&sK[krow * SK5 + kcol] = kreg;
#pragma unroll
    for (int t = 0; t < 8; t++) sVt[(w * 16 + t) * SV5 + pc] = vreg0[t];
#pragma unroll
    for (int t = 0; t < 8; t++) sVt[(w * 16 + 8 + t) * SV5 + pc] = vreg1[t];
#pragma unroll
    for (int t = 0; t < 8; t++) sVt[(w * 16 + t) * SV5 + 64 + pc] = vreg2[t];
#pragma unroll
    for (int t = 0; t < 8; t++) sVt[(w * 16 + 8 + t) * SV5 + 64 + pc] = vreg3[t];
    __syncthreads();
    if (kt + 1 < nkt) LOAD(kt + 1);  // prefetch hides under both phases

#pragma unroll
    for (int hf = 0; hf < 2; hf++) {
      const int st = 2 * kt + hf;
      if (st >= nst) break;
      const int k0 = st * 64;
      const bool mask = (st == qt);

      f16x8 kf[4];
#pragma unroll
      for (int nt = 0; nt < 4; nt++) {
        f16x8 f = {};
        if (quad < 2)
          f = *(const f16x8*)&sK[(hf * 64 + nt * 16 + l16) * SK5 + quad * 8];
        kf[nt] = f;
      }

      // swapped QK^T: lane holds S[key = k0+16nt+4*quad+r][q = gq+l16]
      unsigned wp[4][2];
#pragma unroll
      for (int nt = 0; nt < 4; nt++) {
        f32x4 s = __builtin_amdgcn_mfma_f32_16x16x32_f16(
            kf[nt], qfrag, (f32x4){0.f, 0.f, 0.f, 0.f}, 0, 0, 0);
        float s0 = s[0] * s[0], s1 = s[1] * s[1];
        float s2 = s[2] * s[2], s3 = s[3] * s[3];
        if (mask) {
          const int gkb = k0 + nt * 16 + quad * 4;
          const int qg = gq + l16;
          if (gkb + 0 > qg) s0 = 0.f;
          if (gkb + 1 > qg) s1 = 0.f;
          if (gkb + 2 > qg) s2 = 0.f;
          if (gkb + 3 > qg) s3 = 0.f;
        }
        wp[nt][0] = pack_f16x2(s0, s1);
        wp[nt][1] = pack_f16x2(s2, s3);
      }

      // direct A-fragment packing (no cross-lane): slot(Q,i) holds key
      // kappa = 16*(i>>2) + 4Q + (i&3); V was staged so vf matches.
      u32x4 u0 = {wp[0][0], wp[0][1], wp[1][0], wp[1][1]};
      u32x4 u1 = {wp[2][0], wp[2][1], wp[3][0], wp[3][1]};
      f16x8 af0 = __builtin_bit_cast(f16x8, u0);
      f16x8 af1 = __builtin_bit_cast(f16x8, u1);

#pragma unroll
      for (int nt = 0; nt < 4; nt++) {
        f16x8 vf0 = *(const f16x8*)&sVt[(nt * 16 + l16) * SV5 + hf * 64 + quad * 8];
        f16x8 vf1 = *(const f16x8*)&sVt[(nt * 16 + l16) * SV5 + hf * 64 + 32 + quad * 8];
        oacc[nt] = __builtin_amdgcn_mfma_f32_16x16x32_f16(af0, vf0, oacc[nt], 0, 0, 0);
        oacc[nt] = __builtin_amdgcn_mfma_f32_16x16x32_f16(af1, vf1, oacc[nt], 0, 0, 0);
      }
      zacc = __builtin_amdgcn_mfma_f32_16x16x32_f16(af0, zf0, zacc, 0, 0, 0);
      zacc = __builtin_amdgcn_mfma_f32_16x16x32_f16(af1, zf1, zacc, 0, 0, 0);
    }
  }

  {
    float rz[4];
#pragma unroll
    for (int r = 0; r < 4; r++) {
      float zz = __shfl(zacc[r], lane & 48);
      rz[r] = 1.0f / (zz + 32.0f * EPS);
    }
#pragma unroll
    for (int nt = 0; nt < 4; nt++)
#pragma unroll
      for (int r = 0; r < 4; r++) {
        const int gqr = gq + quad * 4 + r;
        O[(size_t)(b * LL + gqr) * (HH * HD) + h * HD + nt * 16 + l16] =
            (_Float16)(oacc[nt][r] * rz[r]);
      }
  }
}

// ---------------------------------------------------------------------------
// fix_final: exact fp32 ratio for the first NFIX positions per (b,h).
// Standalone launch — round 15 proved fusing into the attention grid costs
// 24% on attention; rounds 6/7 proved fusing into the O-GEMM costs ~15 us
// (codegen perturbation of the GEMM hot loop). It stays standalone.
// ---------------------------------------------------------------------------
__global__ __launch_bounds__(256) void fix_final(
    const float* __restrict__ QKVe, _Float16* __restrict__ Oatt) {
  const int b = blockIdx.x >> 4, h = blockIdx.x & 15;
  const int tid = threadIdx.x;
  const int p = tid >> 6, d = tid & 63;

  float num = 0.f, z = 0.f;
  const float* qrow = QKVe + (size_t)(b * 4 + p) * RQKV + h * FD;
  for (int j = 0; j <= p; j++) {
    const float* krow = QKVe + (size_t)(b * 4 + j) * RQKV + 256 + h * FD;
    float s = 0.f;
#pragma unroll
    for (int f = 0; f < FD; f++) s += qrow[f] * krow[f];
    s *= 0.25f;
    s = s * s;
    z += s;
    num += s * QKVe[(size_t)(b * 4 + j) * RQKV + 512 + h * HD + d];
  }
  Oatt[(size_t)(b * LL + p) * (HH * HD) + h * HD + d] =
      (_Float16)(num / (z + EPS));
}

// ---------------------------------------------------------------------------
// Launch: 5 kernels (round-3 config; GEMM tiles now 128x128).
// ---------------------------------------------------------------------------
extern "C" void kernel_launch(void* const* d_in, const int* in_sizes, int n_in,
                              void* d_out, int out_size, void* d_ws, size_t ws_size,
                              hipStream_t stream) {
  const float* hs = (const float*)d_in[0];  // [4096, 1024]
  const float* Wq = (const float*)d_in[1];  // [1024, 256]
  const float* Wk = (const float*)d_in[2];  // [1024, 256]
  const float* Wv = (const float*)d_in[3];  // [1024, 1024]
  const float* Wo = (const float*)d_in[4];  // [1024, 1024]
  float* out = (float*)d_out;               // [4096, 1024]

  char* ws = (char*)d_ws;
  _Float16* WqkvT = (_Float16*)ws;                    // [1536][1024] = 3 MiB
  _Float16* WoT   = (_Float16*)(ws + (3ull << 20));   // [1024][1024] = 2 MiB
  _Float16* HS16  = (_Float16*)(ws + (5ull << 20));   // [4096][1024] = 8 MiB
  _Float16* QKV   = (_Float16*)(ws + (13ull << 20));  // [4096][1536] = 12 MiB
  _Float16* Oatt  = (_Float16*)(ws + (25ull << 20));  // [4096][1024] = 8 MiB
  float*    QKVe  = (float*)(ws + (33ull << 20));     // [8][1536] fp32

  const int M = BB * LL;  // 4096

  // prep: W transposes + fp32 early-QKV + hs fp32->fp16 cast (one launch)
  prep<<<dim3(3632), 256, 0, stream>>>(Wq, Wk, Wv, Wo, hs, WqkvT, WoT, QKVe, HS16);

  // fused QKV projection: 128x128 tiles
  gemm_f16<_Float16><<<dim3(RQKV / 128, M / 128), 256, 0, stream>>>(
      HS16, WqkvT, QKV, M, RQKV, DD);

  // attention: grid (bh, qt) = 1024 blocks, 5 blocks/CU co-resident
  attn_mfma7<<<dim3(BB * HH, LL / 64), 256, 0, stream>>>(QKV, Oatt);

  // fp32-exact first-NFIX rows per (b,h)
  fix_final<<<dim3(BB * HH), 256, 0, stream>>>(QKVe, Oatt);

  // output projection: 128x128 tiles
  gemm_f16<float><<<dim3(DD / 128, M / 128), 256, 0, stream>>>(
      Oatt, WoT, out, M, DD, DD);
}

// Round 10
// 164.981 us; speedup vs baseline: 1.0404x; 1.0404x over previous
//
#include <hip/hip_runtime.h>
#include <hip/hip_bf16.h>

// Problem constants
#define BB 2
#define LL 2048
#define DD 1024
#define HH 16
#define FD 16
#define HD 64
#define EPS 1e-5f
#define RQKV 1536   // fused QKV row stride (256 Q + 256 K + 1024 V)
#define NFIX 4      // first NFIX positions per (b,h) recomputed in fp32 (low-z rows)

typedef __attribute__((ext_vector_type(4))) float f32x4;
typedef __attribute__((ext_vector_type(8))) _Float16 f16x8;
typedef __attribute__((ext_vector_type(4))) _Float16 f16x4;
typedef __attribute__((ext_vector_type(4))) unsigned int u32x4;

// ---------------------------------------------------------------------------
// prep: fused pre-pass, branch on block range (round-15/16 verified).
//   [0,1536):    transpose+cast [Wq|Wk|Wv] -> WqkvT fp16 [1536][1024]
//   [1536,2560): transpose+cast Wo -> WoT fp16 [1024][1024]
//   [2560,2608): early_qkv — QKVe[8][1536] = hs_early[8][1024] @ W, fp32
//   [2608,3632): cast hs fp32 -> HS16 fp16
//
// SESSION LEDGER (do not re-try without new counter evidence):
//   * FIXA fusion of fix_final into O-GEMM: +15.6 us (rounds 6/7).
//   * balanced-qt y-permutation: no gain (round 6 vs 7).
//   * vtrans pre-transposed V + b64 staging: +1.6 us net (round 4).
//   * permlane-based S^2 transpose: WRONG (round 2).
//   * GEMM 128x128 tiles: +5.9 us (round 9) — K=1024 too short, grid too
//     small (1-1.5 blocks/CU); 128x64 with 768/512 blocks stands.
//   * attn occupancy 2x (rounds 0/1): occupancy doubled, time flat.
//   * round-3 config = 165.6/165.8 us (rounds 3/8): the verified anchor.
//   * round 10: + s_setprio around attn MFMA clusters (T5; m191 evidence).
// ---------------------------------------------------------------------------
__global__ __launch_bounds__(256) void prep(
    const float* __restrict__ Wq, const float* __restrict__ Wk,
    const float* __restrict__ Wv, const float* __restrict__ Wo,
    const float* __restrict__ hs, _Float16* __restrict__ WqkvT,
    _Float16* __restrict__ WoT, float* __restrict__ QKVe,
    _Float16* __restrict__ HS16) {
  __shared__ __attribute__((aligned(16))) char smem[40960];
  const int bx = blockIdx.x;
  const int tid = threadIdx.x;

  if (bx >= 2608) {
    // ---- cast_hs path ----
    int idx = ((bx - 2608) * 256 + tid) * 16;
#pragma unroll
    for (int half = 0; half < 2; half++) {
      float4 a = *(const float4*)(hs + idx + half * 8);
      float4 b = *(const float4*)(hs + idx + half * 8 + 4);
      f16x8 p = {(_Float16)a.x, (_Float16)a.y, (_Float16)a.z, (_Float16)a.w,
                 (_Float16)b.x, (_Float16)b.y, (_Float16)b.z, (_Float16)b.w};
      *(f16x8*)(HS16 + idx + half * 8) = p;
    }
    return;
  }

  if (bx < 2560) {
    // ---- transpose+cast path ----
    _Float16(*s)[40] = (_Float16(*)[40])smem;
    const float* src;
    _Float16* dst;
    int n0, ncol, drow, k0;
    if (bx < 1536) {
      int ct = bx % 48, kt = bx / 48;
      if (ct < 8) { src = Wq; n0 = ct * 32; ncol = 256; drow = n0; }
      else if (ct < 16) { src = Wk; n0 = (ct - 8) * 32; ncol = 256; drow = 256 + n0; }
      else { src = Wv; n0 = (ct - 16) * 32; ncol = 1024; drow = 512 + n0; }
      k0 = kt * 32;
      dst = WqkvT;
    } else {
      int i2 = bx - 1536;
      n0 = (i2 & 31) * 32; k0 = (i2 >> 5) * 32;
      src = Wo; ncol = DD; drow = n0; dst = WoT;
    }
    {
      int r = tid >> 3, c = (tid & 7) * 4;
      float4 v = *(const float4*)(src + (size_t)(k0 + r) * ncol + n0 + c);
      f16x4 p = {(_Float16)v.x, (_Float16)v.y, (_Float16)v.z, (_Float16)v.w};
      *(f16x4*)&s[r][c] = p;
    }
    __syncthreads();
    {
      int n = tid >> 3, kk = (tid & 7) * 4;
      f16x4 o = {s[kk + 0][n], s[kk + 1][n], s[kk + 2][n], s[kk + 3][n]};
      *(f16x4*)(dst + (size_t)(drow + n) * DD + k0 + kk) = o;
    }
    return;
  }

  // ---- early_qkv path ----
  float(*sHS)[DD] = (float(*)[DD])smem;                      // 32 KB
  float(*part)[8][32] = (float(*)[8][32])(smem + 32768);     // 8 KB
  const int kg = tid >> 5, c = tid & 31;
  const int c0 = (bx - 2560) * 32;

  for (int i = tid; i < 8 * (DD / 4); i += 256) {
    int e = i / (DD / 4), col4 = (i % (DD / 4)) * 4;
    int b = e >> 2, r = e & 3;
    *(float4*)&sHS[e][col4] =
        *(const float4*)(hs + (size_t)(b * LL + r) * DD + col4);
  }
  __syncthreads();

  const float* W;
  int col, ncol;
  if (c0 < 256) { W = Wq; col = c0 + c; ncol = 256; }
  else if (c0 < 512) { W = Wk; col = (c0 - 256) + c; ncol = 256; }
  else { W = Wv; col = (c0 - 512) + c; ncol = 1024; }

  float acc[8] = {};
  const int d0 = kg * 128;
#pragma unroll 4
  for (int d = d0; d < d0 + 128; d++) {
    float wv = W[(size_t)d * ncol + col];
#pragma unroll
    for (int e = 0; e < 8; e++) acc[e] += sHS[e][d] * wv;
  }
#pragma unroll
  for (int e = 0; e < 8; e++) part[kg][e][c] = acc[e];
  __syncthreads();

  {
    int e = tid >> 5;
    float t = 0.f;
#pragma unroll
    for (int g = 0; g < 8; g++) t += part[g][e][c];
    QKVe[(size_t)e * RQKV + c0 + c] = t;
  }
}

// ---------------------------------------------------------------------------
// fp16 MFMA GEMM (round-13/16 verified, byte-identical): C = A @ Bt^T.
// 128x64 tile, BK=64, 4 waves (2x2, wave tile 64x32), register prefetch of
// the next 64-K slab. XOR-swizzled LDS (no pad). Measured regressions on
// this kernel: DMA staging, fused fp32-A, 64x64 tiles, FIXA templating
// (+15.6 us), 128x128 tiles (+5.9 us). Keep byte-identical.
// ---------------------------------------------------------------------------
template <typename OutT>
__global__ __launch_bounds__(256) void gemm_f16(
    const _Float16* __restrict__ A, const _Float16* __restrict__ Bt,
    OutT* __restrict__ C, int M, int N, int K) {
  __shared__ __attribute__((aligned(16))) _Float16 sA[128 * 64];  // 16 KB
  __shared__ __attribute__((aligned(16))) _Float16 sB[64 * 64];   // 8 KB
  const int tid = threadIdx.x;
  const int m0 = blockIdx.y * 128, n0 = blockIdx.x * 64;
  const int w = tid >> 6, lane = tid & 63, quad = lane >> 4, l16 = lane & 15;
  const int wm = (w >> 1) * 64, wn = (w & 1) * 32;

  const int sr = tid >> 1, p = tid & 1;     // A: row 0..127, half p
  const int brow = (tid & 127) >> 1;        // B: row 0..63
  const _Float16* Ag = A + (size_t)(m0 + sr) * K + p * 32;
  const _Float16* Bg = Bt + (size_t)(n0 + brow) * K + p * 32;
  _Float16* sAw = &sA[sr * 64];
  _Float16* sBw = &sB[brow * 64];
  const int aswz = sr & 7, bswz = brow & 7;

  f32x4 acc[4][2];
#pragma unroll
  for (int i = 0; i < 4; i++)
#pragma unroll
    for (int j = 0; j < 2; j++) acc[i][j] = (f32x4){0.f, 0.f, 0.f, 0.f};

  f16x8 ar[4], br[4];
  auto LOAD = [&](int k0) {
#pragma unroll
    for (int i = 0; i < 4; i++) ar[i] = *(const f16x8*)(Ag + k0 + i * 8);
    if (tid < 128) {
#pragma unroll
      for (int i = 0; i < 4; i++) br[i] = *(const f16x8*)(Bg + k0 + i * 8);
    }
  };
  LOAD(0);

  for (int k0 = 0; k0 < K; k0 += 64) {
    __syncthreads();
#pragma unroll
    for (int i = 0; i < 4; i++)
      *(f16x8*)(sAw + (((4 * p + i) ^ aswz) * 8)) = ar[i];
    if (tid < 128) {
#pragma unroll
      for (int i = 0; i < 4; i++)
        *(f16x8*)(sBw + (((4 * p + i) ^ bswz) * 8)) = br[i];
    }
    __syncthreads();
    if (k0 + 64 < K) LOAD(k0 + 64);  // prefetch overlaps the MFMAs below

#pragma unroll
    for (int s = 0; s < 2; s++) {
      f16x8 af[4], bf[2];
#pragma unroll
      for (int i = 0; i < 4; i++) {
        int row = wm + i * 16 + l16;
        int col = ((s * 4 + quad) ^ (row & 7)) * 8;
        af[i] = *(const f16x8*)&sA[row * 64 + col];
      }
#pragma unroll
      for (int j = 0; j < 2; j++) {
        int row = wn + j * 16 + l16;
        int col = ((s * 4 + quad) ^ (row & 7)) * 8;
        bf[j] = *(const f16x8*)&sB[row * 64 + col];
      }
#pragma unroll
      for (int i = 0; i < 4; i++)
#pragma unroll
        for (int j = 0; j < 2; j++)
          acc[i][j] = __builtin_amdgcn_mfma_f32_16x16x32_f16(af[i], bf[j], acc[i][j], 0, 0, 0);
    }
  }

#pragma unroll
  for (int i = 0; i < 4; i++)
#pragma unroll
    for (int j = 0; j < 2; j++)
#pragma unroll
      for (int r = 0; r < 4; r++) {
        const int row = m0 + wm + i * 16 + quad * 4 + r;
        const int col = n0 + wn + j * 16 + l16;
        C[(size_t)row * N + col] = (OutT)acc[i][j][r];
      }
}

__device__ __forceinline__ unsigned pack_f16x2(float a, float b) {
  unsigned short ua = __builtin_bit_cast(unsigned short, (_Float16)a);  // RTN
  unsigned short ub = __builtin_bit_cast(unsigned short, (_Float16)b);  // RTN
  return (unsigned)ua | ((unsigned)ub << 16);
}

// ---------------------------------------------------------------------------
// MFMA causal quadratic attention (round-3 verified structure) + round-10
// change: s_setprio(1) wrapped around the QK^T and PV/z MFMA clusters (T5).
// Mechanism: 5 independent blocks/CU at DIFFERENT qt phases — boosting the
// priority of MFMA-entering waves lets them preempt other blocks' staging
// issue (m191: +4-7% on attn with phase-diverse blocks; null only on
// lockstep grids). Pure scheduler hint — no correctness surface; all math,
// layouts, and memory ops byte-identical to the anchor.
// ---------------------------------------------------------------------------
#define SK5 24    // sK row stride: 16 f16 + 8 pad
#define SV5 136   // sVt row stride: 128 keys + 8 pad

__global__ __launch_bounds__(256, 5) void attn_mfma7(
    const _Float16* __restrict__ QKV, _Float16* __restrict__ O) {
  __shared__ __attribute__((aligned(16))) _Float16 sK[128 * SK5];     // 6.0 KB
  __shared__ __attribute__((aligned(16))) _Float16 sVt[80 * SV5];     // 21.25 KB

  const int bh = blockIdx.x;           // fast grid dim: all qt of a bh -> one XCD
  const int b = bh >> 4, h = bh & 15;
  const int qt = 31 - blockIdx.y;      // heavy-first dispatch order
  const int tid = threadIdx.x;
  const int w = tid >> 6;
  const int lane = tid & 63;
  const int quad = lane >> 4;
  const int l16 = lane & 15;
  const int gq = qt * 64 + w * 16;

  // slot-permuted V column for this lane's staged key
  const int pc = (lane & 32) | ((lane & 12) << 1) | ((lane & 16) >> 2) | (lane & 3);

  f16x8 qfrag = {};
  if (quad < 2) {
    qfrag = *(const f16x8*)(QKV +
        (size_t)(b * LL + gq + l16) * RQKV + h * FD + quad * 8);
    const _Float16 RT2 = (_Float16)1.41421356f;
#pragma unroll
    for (int i = 0; i < 8; i++) qfrag[i] = qfrag[i] * RT2;
  }

  // ones rows 64..79 of sVt drive the z row-sum MFMA (all slots = 1 at col 0)
  for (int t = tid; t < 16 * SV5; t += 256) {
    int r = t / SV5, c = t % SV5;
    sVt[64 * SV5 + t] = (_Float16)((r == 0 && c < 128) ? 1.0f : 0.0f);
  }
  __syncthreads();
  const f16x8 zf0 = *(const f16x8*)&sVt[(64 + l16) * SV5 + quad * 8];
  const f16x8 zf1 = *(const f16x8*)&sVt[(64 + l16) * SV5 + 32 + quad * 8];

  f32x4 oacc[4];
  f32x4 zacc = (f32x4){0.f, 0.f, 0.f, 0.f};
#pragma unroll
  for (int nt = 0; nt < 4; nt++) oacc[nt] = (f32x4){0.f, 0.f, 0.f, 0.f};

  const int nst = qt + 1;          // 64-key subtiles needed
  const int nkt = (nst + 1) >> 1;  // 128-key staging tiles

  // 128-key prefetch: K rows via (tid>>1), V rows via lane (two 64-row halves)
  const int krow = tid >> 1, kcol = (tid & 1) * 8;
  f16x8 kreg;
  f16x8 vreg0, vreg1, vreg2, vreg3;
  auto LOAD = [&](int kt) {
    kreg = *(const f16x8*)(QKV +
        (size_t)(b * LL + kt * 128 + krow) * RQKV + 256 + h * FD + kcol);
    const _Float16* vp = QKV +
        (size_t)(b * LL + kt * 128 + lane) * RQKV + 512 + h * HD + w * 16;
    vreg0 = *(const f16x8*)vp;
    vreg1 = *(const f16x8*)(vp + 8);
    vp += (size_t)64 * RQKV;
    vreg2 = *(const f16x8*)vp;
    vreg3 = *(const f16x8*)(vp + 8);
  };
  LOAD(0);

  for (int kt = 0; kt < nkt; kt++) {
    __syncthreads();
    *(f16x8*)&sK[krow * SK5 + kcol] = kreg;
#pragma unroll
    for (int t = 0; t < 8; t++) sVt[(w * 16 + t) * SV5 + pc] = vreg0[t];
#pragma unroll
    for (int t = 0; t < 8; t++) sVt[(w * 16 + 8 + t) * SV5 + pc] = vreg1[t];
#pragma unroll
    for (int t = 0; t < 8; t++) sVt[(w * 16 + t) * SV5 + 64 + pc] = vreg2[t];
#pragma unroll
    for (int t = 0; t < 8; t++) sVt[(w * 16 + 8 + t) * SV5 + 64 + pc] = vreg3[t];
    __syncthreads();
    if (kt + 1 < nkt) LOAD(kt + 1);  // prefetch hides under both phases

#pragma unroll
    for (int hf = 0; hf < 2; hf++) {
      const int st = 2 * kt + hf;
      if (st >= nst) break;
      const int k0 = st * 64;
      const bool mask = (st == qt);

      f16x8 kf[4];
#pragma unroll
      for (int nt = 0; nt < 4; nt++) {
        f16x8 f = {};
        if (quad < 2)
          f = *(const f16x8*)&sK[(hf * 64 + nt * 16 + l16) * SK5 + quad * 8];
        kf[nt] = f;
      }

      // swapped QK^T: lane holds S[key = k0+16nt+4*quad+r][q = gq+l16]
      unsigned wp[4][2];
      __builtin_amdgcn_s_setprio(1);  // T5: favor MFMA-entering wave
#pragma unroll
      for (int nt = 0; nt < 4; nt++) {
        f32x4 s = __builtin_amdgcn_mfma_f32_16x16x32_f16(
            kf[nt], qfrag, (f32x4){0.f, 0.f, 0.f, 0.f}, 0, 0, 0);
        float s0 = s[0] * s[0], s1 = s[1] * s[1];
        float s2 = s[2] * s[2], s3 = s[3] * s[3];
        if (mask) {
          const int gkb = k0 + nt * 16 + quad * 4;
          const int qg = gq + l16;
          if (gkb + 0 > qg) s0 = 0.f;
          if (gkb + 1 > qg) s1 = 0.f;
          if (gkb + 2 > qg) s2 = 0.f;
          if (gkb + 3 > qg) s3 = 0.f;
        }
        wp[nt][0] = pack_f16x2(s0, s1);
        wp[nt][1] = pack_f16x2(s2, s3);
      }
      __builtin_amdgcn_s_setprio(0);

      // direct A-fragment packing (no cross-lane): slot(Q,i) holds key
      // kappa = 16*(i>>2) + 4Q + (i&3); V was staged so vf matches.
      u32x4 u0 = {wp[0][0], wp[0][1], wp[1][0], wp[1][1]};
      u32x4 u1 = {wp[2][0], wp[2][1], wp[3][0], wp[3][1]};
      f16x8 af0 = __builtin_bit_cast(f16x8, u0);
      f16x8 af1 = __builtin_bit_cast(f16x8, u1);

      __builtin_amdgcn_s_setprio(1);  // T5: PV + z cluster
#pragma unroll
      for (int nt = 0; nt < 4; nt++) {
        f16x8 vf0 = *(const f16x8*)&sVt[(nt * 16 + l16) * SV5 + hf * 64 + quad * 8];
        f16x8 vf1 = *(const f16x8*)&sVt[(nt * 16 + l16) * SV5 + hf * 64 + 32 + quad * 8];
        oacc[nt] = __builtin_amdgcn_mfma_f32_16x16x32_f16(af0, vf0, oacc[nt], 0, 0, 0);
        oacc[nt] = __builtin_amdgcn_mfma_f32_16x16x32_f16(af1, vf1, oacc[nt], 0, 0, 0);
      }
      zacc = __builtin_amdgcn_mfma_f32_16x16x32_f16(af0, zf0, zacc, 0, 0, 0);
      zacc = __builtin_amdgcn_mfma_f32_16x16x32_f16(af1, zf1, zacc, 0, 0, 0);
      __builtin_amdgcn_s_setprio(0);
    }
  }

  {
    float rz[4];
#pragma unroll
    for (int r = 0; r < 4; r++) {
      float zz = __shfl(zacc[r], lane & 48);
      rz[r] = 1.0f / (zz + 32.0f * EPS);
    }
#pragma unroll
    for (int nt = 0; nt < 4; nt++)
#pragma unroll
      for (int r = 0; r < 4; r++) {
        const int gqr = gq + quad * 4 + r;
        O[(size_t)(b * LL + gqr) * (HH * HD) + h * HD + nt * 16 + l16] =
            (_Float16)(oacc[nt][r] * rz[r]);
      }
  }
}

// ---------------------------------------------------------------------------
// fix_final: exact fp32 ratio for the first NFIX positions per (b,h).
// Standalone launch — fusing into attention grid costs 24% (prior round 15);
// fusing into O-GEMM costs ~15 us (rounds 6/7). It stays standalone.
// ---------------------------------------------------------------------------
__global__ __launch_bounds__(256) void fix_final(
    const float* __restrict__ QKVe, _Float16* __restrict__ Oatt) {
  const int b = blockIdx.x >> 4, h = blockIdx.x & 15;
  const int tid = threadIdx.x;
  const int p = tid >> 6, d = tid & 63;

  float num = 0.f, z = 0.f;
  const float* qrow = QKVe + (size_t)(b * 4 + p) * RQKV + h * FD;
  for (int j = 0; j <= p; j++) {
    const float* krow = QKVe + (size_t)(b * 4 + j) * RQKV + 256 + h * FD;
    float s = 0.f;
#pragma unroll
    for (int f = 0; f < FD; f++) s += qrow[f] * krow[f];
    s *= 0.25f;
    s = s * s;
    z += s;
    num += s * QKVe[(size_t)(b * 4 + j) * RQKV + 512 + h * HD + d];
  }
  Oatt[(size_t)(b * LL + p) * (HH * HD) + h * HD + d] =
      (_Float16)(num / (z + EPS));
}

// ---------------------------------------------------------------------------
// Launch: 5 kernels (anchor config; attn + setprio only change).
// ---------------------------------------------------------------------------
extern "C" void kernel_launch(void* const* d_in, const int* in_sizes, int n_in,
                              void* d_out, int out_size, void* d_ws, size_t ws_size,
                              hipStream_t stream) {
  const float* hs = (const float*)d_in[0];  // [4096, 1024]
  const float* Wq = (const float*)d_in[1];  // [1024, 256]
  const float* Wk = (const float*)d_in[2];  // [1024, 256]
  const float* Wv = (const float*)d_in[3];  // [1024, 1024]
  const float* Wo = (const float*)d_in[4];  // [1024, 1024]
  float* out = (float*)d_out;               // [4096, 1024]

  char* ws = (char*)d_ws;
  _Float16* WqkvT = (_Float16*)ws;                    // [1536][1024] = 3 MiB
  _Float16* WoT   = (_Float16*)(ws + (3ull << 20));   // [1024][1024] = 2 MiB
  _Float16* HS16  = (_Float16*)(ws + (5ull << 20));   // [4096][1024] = 8 MiB
  _Float16* QKV   = (_Float16*)(ws + (13ull << 20));  // [4096][1536] = 12 MiB
  _Float16* Oatt  = (_Float16*)(ws + (25ull << 20));  // [4096][1024] = 8 MiB
  float*    QKVe  = (float*)(ws + (33ull << 20));     // [8][1536] fp32

  const int M = BB * LL;  // 4096

  // prep: W transposes + fp32 early-QKV + hs fp32->fp16 cast (one launch)
  prep<<<dim3(3632), 256, 0, stream>>>(Wq, Wk, Wv, Wo, hs, WqkvT, WoT, QKVe, HS16);

  // fused QKV projection: 128x64 tiles (verified optimum)
  gemm_f16<_Float16><<<dim3(RQKV / 64, M / 128), 256, 0, stream>>>(
      HS16, WqkvT, QKV, M, RQKV, DD);

  // attention: grid (bh, qt) = 1024 blocks, 5 blocks/CU co-resident
  attn_mfma7<<<dim3(BB * HH, LL / 64), 256, 0, stream>>>(QKV, Oatt);

  // fp32-exact first-NFIX rows per (b,h)
  fix_final<<<dim3(BB * HH), 256, 0, stream>>>(QKVe, Oatt);

  // output projection: 128x64 tiles
  gemm_f16<float><<<dim3(DD / 64, M / 128), 256, 0, stream>>>(
      Oatt, WoT, out, M, DD, DD);
}